// Round 1
// baseline (510.886 us; speedup 1.0000x reference)
//
#include <hip/hip_runtime.h>
#include <hip/hip_cooperative_groups.h>
#include <cstdint>

namespace cg = cooperative_groups;

// ---------------------------------------------------------------------------
// NeuralODE (DoPri5 adaptive, 64-iter budget) on MI355X.
// Decomposition: WG = batch row (256 WGs), thread = feature column (256 thr).
// All 7 RK stages of an iteration are row-local -> only 1 grid.sync()/iter
// (for the global err_norm reduction). FSAL: k0 <- k6 on accept. Early break
// when t >= 1.0 (reference freezes state when done, so this is exact).
// Weights packed to bf16 in d_ws once per launch (prologue, all WGs).
// ---------------------------------------------------------------------------

#define WS_W1P_OFF 0
#define WS_W2P_OFF (512 * 1024)
#define WS_ERR_OFF (1024 * 1024)

__device__ __forceinline__ float bflo(uint32_t u) {
  union { uint32_t i; float f; } v; v.i = u << 16; return v.f;
}
__device__ __forceinline__ float bfhi(uint32_t u) {
  union { uint32_t i; float f; } v; v.i = u & 0xffff0000u; return v.f;
}
__device__ __forceinline__ uint32_t bfpack(float a, float b) {
  union { float f; uint32_t i; } ua, ub;
  ua.f = a; ub.f = b;
  uint32_t x = ua.i + (0x7fffu + ((ua.i >> 16) & 1u));  // RNE to bf16
  uint32_t y = ub.i + (0x7fffu + ((ub.i >> 16) & 1u));
  return (x >> 16) | (y & 0xffff0000u);
}

// f(x, t) for one batch row. 256 threads; thread `tid` owns output column tid
// and 4 hidden units [4*tid, 4*tid+3].
__device__ __forceinline__ float eval_vf(
    float xi_c, float t_i, int tid,
    const uint4* __restrict__ W1p, const uint4* __restrict__ W2p,
    const float* __restrict__ w1t, const float* __restrict__ b1,
    const float* __restrict__ b2, float* sxi, float* sh) {
  sxi[tid] = xi_c;
  __syncthreads();

  // GEMM1: h[4t..4t+3] = tanh(xi . W1[:, j] + t * W1[256, j] + b1[j])
  const float4 bv = reinterpret_cast<const float4*>(const_cast<float*>(b1))[tid];
  const float4 wt = reinterpret_cast<const float4*>(const_cast<float*>(w1t))[tid];
  float a0 = fmaf(t_i, wt.x, bv.x);
  float a1 = fmaf(t_i, wt.y, bv.y);
  float a2 = fmaf(t_i, wt.z, bv.z);
  float a3 = fmaf(t_i, wt.w, bv.w);
  const float2* sxi2 = reinterpret_cast<const float2*>(sxi);
#pragma unroll 4
  for (int c2 = 0; c2 < 128; ++c2) {
    uint4 w = W1p[(c2 << 8) + tid];   // rows 2c2,2c2+1 x cols 4t..4t+3 (bf16)
    float2 xv = sxi2[c2];             // LDS broadcast
    a0 = fmaf(xv.x, bflo(w.x), a0);
    a1 = fmaf(xv.x, bfhi(w.x), a1);
    a2 = fmaf(xv.x, bflo(w.y), a2);
    a3 = fmaf(xv.x, bfhi(w.y), a3);
    a0 = fmaf(xv.y, bflo(w.z), a0);
    a1 = fmaf(xv.y, bfhi(w.z), a1);
    a2 = fmaf(xv.y, bflo(w.w), a2);
    a3 = fmaf(xv.y, bfhi(w.w), a3);
  }
  float4 hv;
  hv.x = tanhf(a0); hv.y = tanhf(a1); hv.z = tanhf(a2); hv.w = tanhf(a3);
  reinterpret_cast<float4*>(sh)[tid] = hv;
  __syncthreads();

  // GEMM2: k[t] = h . W2[:, t] + b2[t]
  float acc = b2[tid];
  const float4* sh4 = reinterpret_cast<const float4*>(sh);
#pragma unroll 4
  for (int k4 = 0; k4 < 128; ++k4) {
    uint4 w = W2p[(k4 << 8) + tid];   // rows 8k4..8k4+7 at col t (bf16)
    float4 h0 = sh4[2 * k4];
    float4 h1 = sh4[2 * k4 + 1];
    acc = fmaf(h0.x, bflo(w.x), acc);
    acc = fmaf(h0.y, bfhi(w.x), acc);
    acc = fmaf(h0.z, bflo(w.y), acc);
    acc = fmaf(h0.w, bfhi(w.y), acc);
    acc = fmaf(h1.x, bflo(w.z), acc);
    acc = fmaf(h1.y, bfhi(w.z), acc);
    acc = fmaf(h1.z, bflo(w.w), acc);
    acc = fmaf(h1.w, bfhi(w.w), acc);
  }
  return acc;
}

extern "C" __global__ void __launch_bounds__(256) neural_ode_dopri5(
    const float* __restrict__ x0, const float* __restrict__ W1,
    const float* __restrict__ b1, const float* __restrict__ W2,
    const float* __restrict__ b2, float* __restrict__ out,
    uint4* __restrict__ W1p, uint4* __restrict__ W2p, float* errAcc) {
  cg::grid_group gridg = cg::this_grid();
  const int tid = threadIdx.x;
  const int row = blockIdx.x;
  const int g = (row << 8) + tid;

  // ---- prologue: pack weights to bf16 in workspace; zero err slots --------
  if (g < 32768) {
    // W1p[c2*256 + jq] = {W1[2c2][4jq..+3], W1[2c2+1][4jq..+3]} as 8 bf16
    const int c2 = g >> 8, jq = g & 255;
    const float* r0 = W1 + (2 * c2) * 1024 + 4 * jq;
    float4 a = *reinterpret_cast<const float4*>(r0);
    float4 b = *reinterpret_cast<const float4*>(r0 + 1024);
    W1p[g] = make_uint4(bfpack(a.x, a.y), bfpack(a.z, a.w),
                        bfpack(b.x, b.y), bfpack(b.z, b.w));
  } else {
    // W2p[k4*256 + c] = W2[8k4..8k4+7][c] as 8 bf16
    const int idx = g - 32768;
    const int k4 = idx >> 8, c = idx & 255;
    const float* base = W2 + (8 * k4) * 256 + c;
    W2p[idx] = make_uint4(bfpack(base[0], base[256]),
                          bfpack(base[512], base[768]),
                          bfpack(base[1024], base[1280]),
                          bfpack(base[1536], base[1792]));
  }
  if (g < 64) errAcc[g] = 0.0f;
  gridg.sync();

  // ---- Butcher tableau (exact float64 -> float32, matching the reference) -
  const float a20 = (float)(3.0 / 40.0),      a21 = (float)(9.0 / 40.0);
  const float a30 = (float)(44.0 / 45.0),     a31 = (float)(-56.0 / 15.0);
  const float a32 = (float)(32.0 / 9.0);
  const float a40 = (float)(19372.0 / 6561.0), a41 = (float)(-25360.0 / 2187.0);
  const float a42 = (float)(64448.0 / 6561.0), a43 = (float)(-212.0 / 729.0);
  const float a50 = (float)(9017.0 / 3168.0),  a51 = (float)(-355.0 / 33.0);
  const float a52 = (float)(46732.0 / 5247.0), a53 = (float)(49.0 / 176.0);
  const float a54 = (float)(-5103.0 / 18656.0);
  const float b50 = (float)(35.0 / 384.0),     b52 = (float)(500.0 / 1113.0);
  const float b53 = (float)(125.0 / 192.0),    b54 = (float)(-2187.0 / 6784.0);
  const float b55 = (float)(11.0 / 84.0);
  const float c1 = (float)(1.0 / 5.0), c2c = (float)(3.0 / 10.0);
  const float c3 = (float)(4.0 / 5.0), c4c = (float)(8.0 / 9.0);
  const float d0 = (float)(35.0 / 384.0 - 5179.0 / 57600.0);
  const float d2 = (float)(500.0 / 1113.0 - 7571.0 / 16695.0);
  const float d3 = (float)(125.0 / 192.0 - 393.0 / 640.0);
  const float d4 = (float)(-2187.0 / 6784.0 + 92097.0 / 339200.0);
  const float d5 = (float)(11.0 / 84.0 - 187.0 / 2100.0);
  const float d6 = (float)(-1.0 / 40.0);

  __shared__ float sxi[256];
  __shared__ float sh[1024];
  __shared__ float sred[4];

  const float* w1t = W1 + 256 * 1024;  // time row of W1
  const float x0v = x0[g];
  float x = x0v;
  float t = 0.0f, dt = 0.05f;

  // FSAL seed: k0 = f(x0, 0)
  float k0 = eval_vf(x, 0.0f, tid, W1p, W2p, w1t, b1, b2, sxi, sh);
  float k1, k2, k3, k4, k5, k6;

  for (int it = 0; it < 64; ++it) {
    if (t >= 1.0f) break;  // reference freezes all state once done -> exact
    float dt_c = fmaxf(fminf(dt, 1.0f - t), 0.0f);

    float xi = fmaf(dt_c * 0.2f, k0, x);
    k1 = eval_vf(xi, fmaf(c1, dt_c, t), tid, W1p, W2p, w1t, b1, b2, sxi, sh);

    xi = fmaf(dt_c * a21, k1, fmaf(dt_c * a20, k0, x));
    k2 = eval_vf(xi, fmaf(c2c, dt_c, t), tid, W1p, W2p, w1t, b1, b2, sxi, sh);

    xi = fmaf(dt_c * a32, k2, fmaf(dt_c * a31, k1, fmaf(dt_c * a30, k0, x)));
    k3 = eval_vf(xi, fmaf(c3, dt_c, t), tid, W1p, W2p, w1t, b1, b2, sxi, sh);

    xi = fmaf(dt_c * a43, k3,
         fmaf(dt_c * a42, k2, fmaf(dt_c * a41, k1, fmaf(dt_c * a40, k0, x))));
    k4 = eval_vf(xi, fmaf(c4c, dt_c, t), tid, W1p, W2p, w1t, b1, b2, sxi, sh);

    xi = fmaf(dt_c * a54, k4, fmaf(dt_c * a53, k3,
         fmaf(dt_c * a52, k2, fmaf(dt_c * a51, k1, fmaf(dt_c * a50, k0, x)))));
    k5 = eval_vf(xi, t + dt_c, tid, W1p, W2p, w1t, b1, b2, sxi, sh);

    // stage 7 point == x5 (FSAL: A[6] == B5)
    float x5 = fmaf(dt_c * b55, k5, fmaf(dt_c * b54, k4,
               fmaf(dt_c * b53, k3, fmaf(dt_c * b52, k2,
               fmaf(dt_c * b50, k0, x)))));
    k6 = eval_vf(x5, t + dt_c, tid, W1p, W2p, w1t, b1, b2, sxi, sh);

    // embedded error estimate and global RMS reduction
    float err = fmaf(dt_c * d6, k6, fmaf(dt_c * d5, k5, fmaf(dt_c * d4, k4,
                fmaf(dt_c * d3, k3, fmaf(dt_c * d2, k2, dt_c * d0 * k0)))));
    float scale = fmaf(1e-3f, fmaxf(fabsf(x), fabsf(x5)), 1e-4f);
    float r = err / scale;
    float loc = r * r;
#pragma unroll
    for (int o = 32; o > 0; o >>= 1) loc += __shfl_down(loc, o);
    if ((tid & 63) == 0) sred[tid >> 6] = loc;
    __syncthreads();
    if (tid == 0)
      atomicAdd(&errAcc[it], sred[0] + sred[1] + sred[2] + sred[3]);
    gridg.sync();

    // every WG recomputes the (identical) controller decision
    float total = __hip_atomic_load(&errAcc[it], __ATOMIC_RELAXED,
                                    __HIP_MEMORY_SCOPE_AGENT);
    float err_norm = sqrtf(total * (1.0f / 65536.0f));
    bool accept = err_norm <= 1.0f;
    float factor = 0.9f * powf(err_norm + 1e-10f, -0.2f);
    factor = fminf(fmaxf(factor, 0.2f), 5.0f);
    if (accept) { t = t + dt_c; x = x5; k0 = k6; }  // FSAL reuse
    dt = dt_c * factor;
  }

  // output: stack([x0, xf])
  out[g] = x0v;
  out[65536 + g] = x;
}

extern "C" void kernel_launch(void* const* d_in, const int* in_sizes, int n_in,
                              void* d_out, int out_size, void* d_ws,
                              size_t ws_size, hipStream_t stream) {
  const float* x0 = (const float*)d_in[0];
  const float* W1 = (const float*)d_in[1];
  const float* b1 = (const float*)d_in[2];
  const float* W2 = (const float*)d_in[3];
  const float* b2 = (const float*)d_in[4];
  float* out = (float*)d_out;
  char* ws = (char*)d_ws;
  uint4* W1p = (uint4*)(ws + WS_W1P_OFF);
  uint4* W2p = (uint4*)(ws + WS_W2P_OFF);
  float* errAcc = (float*)(ws + WS_ERR_OFF);

  void* args[] = {&x0, &W1, &b1, &W2, &b2, &out, &W1p, &W2p, &errAcc};
  hipLaunchCooperativeKernel((void*)neural_ode_dopri5, dim3(256), dim3(256),
                             args, 0, stream);
}